// Round 1
// 875.546 us; speedup vs baseline: 1.0360x; 1.0360x over previous
//
#include <hip/hip_runtime.h>

namespace {

constexpr int T_LEN = 2048;
constexpr int B_TOT = 2048;
constexpr int H1 = 36;
constexpr int NB = 16;      // batches per block = MFMA N
constexpr int BLOCK = 640;  // 9 A-waves (M-tiles) + 1 L2 wave
constexpr int RS = 72;      // hT row stride in halves: 144B = 36 dwords == 4 (mod 32)
                            // -> successive batch rows cycle all 8 bank-quads: <=2-way
                            // conflict on ds_read_b128 (RS=80 was 4-way, 1e2 cyc/step)

typedef _Float16 f16x8 __attribute__((ext_vector_type(8)));
typedef _Float16 h16x2 __attribute__((ext_vector_type(2)));
typedef float f32x4 __attribute__((ext_vector_type(4)));

__device__ __forceinline__ float fdot2(float wb, float hb, float acc) {
#if __has_builtin(__builtin_amdgcn_fdot2)
  return __builtin_amdgcn_fdot2(__builtin_bit_cast(h16x2, wb),
                                __builtin_bit_cast(h16x2, hb), acc, false);
#else
  float d;
  asm("v_dot2_f32_f16 %0, %1, %2, %3" : "=v"(d) : "v"(wb), "v"(hb), "0"(acc));
  return d;
#endif
}
__device__ __forceinline__ float pack2h(float a, float b) {
  h16x2 t = {(_Float16)a, (_Float16)b};
  return __builtin_bit_cast(float, t);
}
// Quad-broadcast via DPP quad_perm: VALU full-rate, stays OFF the LDS pipe
// (ds_swizzle had ~LDS latency and contended with the A-waves' b128 reads).
template <int CTRL>
__device__ __forceinline__ float qb(float v) {
  return __builtin_bit_cast(
      float, __builtin_amdgcn_update_dpp(0, __builtin_bit_cast(int, v), CTRL,
                                         0xf, 0xf, true));
}
__device__ __forceinline__ float fexp2(float x) { return __builtin_amdgcn_exp2f(x); }
__device__ __forceinline__ float frcp(float x) { return __builtin_amdgcn_rcpf(x); }
__device__ __forceinline__ float sigm(float x) { return frcp(1.f + fexp2(x * -1.44269504f)); }
__device__ __forceinline__ float tanh_fast(float x) {
  return fmaf(2.f, frcp(1.f + fexp2(x * -2.88539008f)), -1.f);  // 2*sigm(2x)-1
}

// Barrier WITHOUT the vmcnt(0)/expcnt(0) drain that __syncthreads() emits.
// Cross-wave data flows only through LDS, so producer-side lgkmcnt(0) before
// s_barrier is sufficient. This keeps the x prefetch (global loads) and the
// out stores in flight across step barriers instead of draining a ~300-900 cy
// HBM round-trip into every 4th step.
__device__ __forceinline__ void step_sync() {
  asm volatile("s_waitcnt lgkmcnt(0)" ::: "memory");  // ds_writes retired
  __builtin_amdgcn_s_barrier();
  __builtin_amdgcn_sched_barrier(0);   // don't hoist next step's ds_reads above
  asm volatile("" ::: "memory");
}

__global__ __launch_bounds__(BLOCK) void lstm2_kernel(
    const float* __restrict__ x, const float* __restrict__ Wih1,
    const float* __restrict__ Whh1, const float* __restrict__ bih1,
    const float* __restrict__ bhh1, const float* __restrict__ Wih2,
    const float* __restrict__ Whh2, const float* __restrict__ bih2,
    const float* __restrict__ bhh2, float* __restrict__ out)
{
  // lds[buf][0]=h1 fp16 (B-layout: [batch n][k=unit]), lds[buf][1]=relu(h1)
  __shared__ __align__(16) _Float16 lds[2][2][NB][RS];

  const int tid = threadIdx.x;
  const int wid = tid >> 6;
  const int lane = tid & 63;
  const int g0 = blockIdx.x * NB;
  const bool isA = wid < 9;

  for (int i = tid; i < 2 * 2 * NB * RS; i += BLOCK)
    ((_Float16*)lds)[i] = (_Float16)0.f;  // h_{-1}=0 and zero-pad k>=36
  __syncthreads();

  // ---- A-wave (tile wid: units u0..u0+3, all 4 gates, 16 batches) ----
  const int m = lane & 15;   // A: row index / B,C: batch col
  const int q = lane >> 4;   // A,B: k-group / C: row group
  f16x8 A0 = {}, A1 = {};
  float wxc[4] = {0, 0, 0, 0}, bxc[4] = {0, 0, 0, 0};
  float c1 = 0.f;
  const float* xc = nullptr;
  if (isA) {
    const int u0 = wid * 4;
    // A[mrow][k]: mrow = uloc*4+g  ->  original row r = g*36 + (u0+uloc)
    const int ra = (m & 3) * H1 + (u0 + (m >> 2));
#pragma unroll
    for (int j = 0; j < 8; ++j) {
      A0[j] = (_Float16)Whh1[ra * H1 + q * 8 + j];  // k = q*8+j <= 31 < 36
      const int k1 = 32 + q * 8 + j;
      A1[j] = (k1 < H1) ? (_Float16)Whh1[ra * H1 + k1] : (_Float16)0.f;
    }
    // C rows held by this lane: mrow = q*4+reg -> unit u0+q, gate reg
#pragma unroll
    for (int r = 0; r < 4; ++r) {
      const int rc = r * H1 + (u0 + q);
      wxc[r] = Wih1[rc];
      bxc[r] = bih1[rc] + bhh1[rc];
    }
    xc = x + (size_t)(g0 + m) * T_LEN;
  }

  // ---- L2 wave: lane = batch*4 + gate ----
  const int lb = lane >> 2, lg = lane & 3;
  float w2[18];
  float whg = 0.f, b2 = 0.f, c2 = 0.f, h2 = 0.f;
  float* outp = nullptr;
#pragma unroll
  for (int k = 0; k < 18; ++k) w2[k] = 0.f;
  if (!isA) {
    const float* wr = Wih2 + lg * H1;
#pragma unroll
    for (int k = 0; k < 18; ++k) w2[k] = pack2h(wr[2 * k], wr[2 * k + 1]);
    whg = Whh2[lg];
    b2 = bih2[lg] + bhh2[lg];
    outp = out + (size_t)(g0 + lb) * T_LEN;
  }

  float4 qx = make_float4(0.f, 0.f, 0.f, 0.f);
  if (isA) qx = *(const float4*)xc;  // x[0..3]
  float4 ov = make_float4(0.f, 0.f, 0.f, 0.f);

  // One iteration: A-waves compute h_i from h_{i-1}; L2 wave computes out[i-1].
  // Single barrier/step is safe: step s reads buf[(s+1)&1] and writes buf[s&1],
  // so within a step read/write buffers never collide, and the barrier orders
  // the cross-wave handoff between steps.
  auto step = [&](int i, float xv, int s) {
    const int ib = (s + 1) & 1;  // holds h_{i-1}
    const int wb = s & 1;
    if (isA) {
      const f16x8 B0 = *(const f16x8*)&lds[ib][0][m][q * 8];        // k=q*8..+7
      const f16x8 B1 = *(const f16x8*)&lds[ib][0][m][32 + q * 8];   // zeros pad k>=36
      f32x4 cc;
#pragma unroll
      for (int r = 0; r < 4; ++r) cc[r] = fmaf(xv, wxc[r], bxc[r]);
      cc = __builtin_amdgcn_mfma_f32_16x16x32_f16(A0, B0, cc, 0, 0, 0);
      cc = __builtin_amdgcn_mfma_f32_16x16x32_f16(A1, B1, cc, 0, 0, 0);
      const float I = sigm(cc[0]), F = sigm(cc[1]);
      const float G = tanh_fast(cc[2]), O = sigm(cc[3]);
      c1 = fmaf(F, c1, I * G);
      const float h = O * tanh_fast(c1);
      const int ku = (wid << 2) + q;  // this lane's unit
      lds[wb][0][m][ku] = (_Float16)h;
      lds[wb][1][m][ku] = (_Float16)fmaxf(h, 0.f);
    } else if (i > 0) {
      const char* rp = (const char*)&lds[ib][1][lb][0];  // relu(h_{i-1}), row lb
      const float4 r0 = *(const float4*)rp;
      const float4 r1 = *(const float4*)(rp + 16);
      const float4 r2 = *(const float4*)(rp + 32);
      const float4 r3 = *(const float4*)(rp + 48);
      const float2 r4 = *(const float2*)(rp + 64);
      const float f[18] = {r0.x, r0.y, r0.z, r0.w, r1.x, r1.y, r1.z, r1.w,
                           r2.x, r2.y, r2.z, r2.w, r3.x, r3.y, r3.z, r3.w,
                           r4.x, r4.y};
      float aE = 0.f, aO = 0.f;  // two accs: halve the dot dep-chain
#pragma unroll
      for (int k = 0; k < 18; k += 2) aE = fdot2(w2[k], f[k], aE);
#pragma unroll
      for (int k = 1; k < 18; k += 2) aO = fdot2(w2[k], f[k], aO);
      const float pre = (aE + aO) + fmaf(h2, whg, b2);  // this lane's gate lg
      const float pI = qb<0x00>(pre);  // quad-broadcast lane 0 (i) via DPP
      const float pF = qb<0x55>(pre);  // lane 1 (f)
      const float pG = qb<0xAA>(pre);  // lane 2 (g)
      const float pO = qb<0xFF>(pre);  // lane 3 (o)
      c2 = fmaf(sigm(pF), c2, sigm(pI) * tanh_fast(pG));
      h2 = sigm(pO) * tanh_fast(c2);  // = out[i-1], replicated in quad
      if (s == 1) ov.x = h2;
      else if (s == 2) ov.y = h2;
      else if (s == 3) ov.z = h2;
      else {
        ov.w = h2;
        if (lg == 0) *(float4*)(outp + (i - 4)) = ov;  // out[i-4..i-1]
      }
    }
    step_sync();
  };

  for (int i0 = 0; i0 < T_LEN; i0 += 4) {
    float4 qn = qx;
    if (isA) {  // prefetch next x quad (clamped; tail value unused garbage-OK)
      const int tn = (i0 + 4 < T_LEN) ? (i0 + 4) : (T_LEN - 4);
      qn = *(const float4*)(xc + tn);
    }
    step(i0 + 0, qx.x, 0);
    step(i0 + 1, qx.y, 1);
    step(i0 + 2, qx.z, 2);
    step(i0 + 3, qx.w, 3);
    qx = qn;
  }
  // Final iter i=2048: A-waves compute a discarded h_2048; L2 emits out[2047]
  // and stores out[2044..2047].
  step(T_LEN, qx.x, 0);
}

}  // namespace

extern "C" void kernel_launch(void* const* d_in, const int* in_sizes, int n_in,
                              void* d_out, int out_size, void* d_ws, size_t ws_size,
                              hipStream_t stream) {
  const float* x    = (const float*)d_in[0];
  const float* Wih1 = (const float*)d_in[1];
  const float* Whh1 = (const float*)d_in[2];
  const float* bih1 = (const float*)d_in[3];
  const float* bhh1 = (const float*)d_in[4];
  const float* Wih2 = (const float*)d_in[5];
  const float* Whh2 = (const float*)d_in[6];
  const float* bih2 = (const float*)d_in[7];
  const float* bhh2 = (const float*)d_in[8];
  float* out = (float*)d_out;

  dim3 grid(B_TOT / NB);  // 128 blocks x 16 batches
  dim3 block(BLOCK);      // 9 MFMA waves + 1 L2 wave
  hipLaunchKernelGGL(lstm2_kernel, grid, block, 0, stream,
                     x, Wih1, Whh1, bih1, bhh1, Wih2, Whh2, bih2, bhh2, out);
}